// Round 5
// baseline (334.782 us; speedup 1.0000x reference)
//
#include <hip/hip_runtime.h>
#include <stdint.h>

// Problem constants (match reference)
#define M_PRED 100
#define N_GT 20
#define PER4 160000          // 800*800/4 float4s per mask
#define IOU_THR_F 0.5f
#define SCORE_THR_F 0.05f

typedef float f32x4 __attribute__((ext_vector_type(4)));

// ---------------------------------------------------------------------------
// Single fused kernel. EVERY block redundantly computes the tiny greedy match
// (deterministic: same inputs, same f32 ops, same result in every block), so
// no inter-kernel dependency / workspace / second launch is needed. Match
// cost is latency-bound (~2 us) and overlaps across all co-resident blocks;
// the streaming phase then moves 51.2 MB read + 51.2 MB write at HBM rate.
//
// Match replica notes (faithful to the reference, including its quirk):
//  - availability check is `gtm <= 0` (a GT matched to pred 0 stays
//    available and can be re-matched by a later candidate)
//  - jnp.argmax first-max tie rule -> lowest j among exact-equal maxima
//  - stable descending score sort (ties by original index ascending)
//  - score < SCORE_THR candidates change no state -> safe to pre-filter
// ---------------------------------------------------------------------------
__global__ __launch_bounds__(256) void fused_kernel(
    const float* __restrict__ pred_boxes,   // [M,4] xyxy
    const float* __restrict__ pred_scores,  // [M]
    const float* __restrict__ mask_score,   // [M]
    const f32x4* __restrict__ pred_masks,   // [M, PER4]
    const float* __restrict__ gt_boxes,     // [N,4] xyxy
    f32x4* __restrict__ out_masks,          // [N, PER4]
    float* __restrict__ out_flags,          // [N]
    float* __restrict__ out_scores)         // [N]
{
    __shared__ float s_iou[M_PRED * N_GT];
    __shared__ float s_gb[N_GT * 4];
    __shared__ float s_scores[M_PRED];
    __shared__ int   s_order[M_PRED];   // rank -> pred idx (stable desc sort)
    __shared__ int   s_cand[M_PRED];    // candidate flag per pred
    __shared__ int   s_order2[M_PRED];  // compacted candidates, score order
    __shared__ int   s_wcnt[2];         // per-wave candidate counts
    __shared__ int   s_ncand;
    __shared__ int   s_gtm[N_GT];

    const int tid = threadIdx.x;

    // ---- Phase 0: stage GT boxes + scores (disjoint thread ranges) ----
    if (tid < N_GT * 4) s_gb[tid] = gt_boxes[tid];
    if (tid >= 128 && tid < 128 + M_PRED) s_scores[tid - 128] = pred_scores[tid - 128];
    __syncthreads();

    // ---- Phase 1: per-pred IoU row + stable rank + candidate flag ----
    if (tid < M_PRED) {
        f32x4 b = ((const f32x4*)pred_boxes)[tid];  // x0 y0 x1 y1
        float area1 = (b.z - b.x) * (b.w - b.y);
        float mx = 0.0f;
        #pragma unroll
        for (int j = 0; j < N_GT; ++j) {
            float bx0 = s_gb[j * 4 + 0], by0 = s_gb[j * 4 + 1];
            float bx1 = s_gb[j * 4 + 2], by1 = s_gb[j * 4 + 3];
            float area2 = (bx1 - bx0) * (by1 - by0);
            float lx = fmaxf(b.x, bx0), ly = fmaxf(b.y, by0);
            float rx = fminf(b.z, bx1), ry = fminf(b.w, by1);
            float w = fmaxf(rx - lx, 0.0f), h = fmaxf(ry - ly, 0.0f);
            float inter = w * h;
            float uni = area1 + area2 - inter;
            float iou = inter / fmaxf(uni, 1e-6f);
            s_iou[tid * N_GT + j] = iou;
            mx = fmaxf(mx, iou);
        }
        float si = s_scores[tid];
        int r = 0;
        for (int k = 0; k < M_PRED; ++k) {
            float sk = s_scores[k];
            r += (sk > si || (sk == si && k < tid)) ? 1 : 0;
        }
        s_order[r] = tid;
        s_cand[tid] = (si >= SCORE_THR_F && mx >= IOU_THR_F) ? 1 : 0;
    }
    __syncthreads();

    // ---- Phase 2: parallel compaction via ballot prefix-sum (2 waves) ----
    int  i_pred = -1;
    bool f = false;
    int  pos = 0;
    if (tid < 128) {
        if (tid < M_PRED) { i_pred = s_order[tid]; f = (s_cand[i_pred] != 0); }
        unsigned long long mb = __ballot(f);
        int lane = tid & 63;
        pos = __popcll(mb & ((1ull << lane) - 1ull));
        if (lane == 0) s_wcnt[tid >> 6] = __popcll(mb);
    }
    __syncthreads();
    if (f) {
        int base = (tid >= 64) ? s_wcnt[0] : 0;
        s_order2[base + pos] = i_pred;
    }
    if (tid == 0) s_ncand = s_wcnt[0] + s_wcnt[1];
    __syncthreads();

    // ---- Phase 3: greedy match, 32-lane shuffle reduce per candidate ----
    if (tid < 32) {
        const int lane = tid;
        const bool is_gt = lane < N_GT;
        int gtm_j = -1;
        const int nc = s_ncand;
        for (int r = 0; r < nc; ++r) {
            int icur = s_order2[r];
            float v = is_gt ? s_iou[icur * N_GT + lane] : -1.0f;
            // Reference quirk: availability is `gtm <= 0`.
            bool valid = is_gt && (gtm_j <= 0) && (v >= IOU_THR_F);
            float x = valid ? v : -1.0f;
            #pragma unroll
            for (int d = 1; d < 32; d <<= 1)
                x = fmaxf(x, __shfl_xor(x, d, 32));
            unsigned long long mb = __ballot(valid && (v == x));
            if (mb != 0ull) {
                int bj = (int)__builtin_ctzll(mb);  // lowest j achieving max
                if (lane == bj) gtm_j = icur;
            }
        }
        if (is_gt) {
            s_gtm[lane] = gtm_j;
            if (blockIdx.x == 0) {  // one block writes the small outputs
                bool matched = gtm_j > -1;
                int idx = matched ? gtm_j : 0;
                out_flags[lane]  = matched ? mask_score[idx] : 0.0f;
                out_scores[lane] = matched ? s_scores[idx]   : 0.0f;
            }
        }
    }
    __syncthreads();

    // ---- Phase 4: stream masks (grid-stride, 1 float4/thread/iter) ----
    const int total = N_GT * PER4;  // 3,200,000 float4s
    for (int t = blockIdx.x * 256 + tid; t < total; t += gridDim.x * 256) {
        unsigned ut = (unsigned)t;
        int j = (int)(ut / PER4);           // magic-mul division
        int k = (int)(ut - (unsigned)j * PER4);
        int g = s_gtm[j];
        f32x4 v = {0.0f, 0.0f, 0.0f, 0.0f};
        if (g > -1)
            v = __builtin_nontemporal_load(&pred_masks[(size_t)g * PER4 + k]);
        __builtin_nontemporal_store(v, &out_masks[(size_t)j * PER4 + k]);
    }
}

extern "C" void kernel_launch(void* const* d_in, const int* in_sizes, int n_in,
                              void* d_out, int out_size, void* d_ws, size_t ws_size,
                              hipStream_t stream) {
    const float* pred_boxes  = (const float*)d_in[0];  // [100,4]
    const float* pred_scores = (const float*)d_in[1];  // [100]
    const float* mask_score  = (const float*)d_in[2];  // [100]
    const float* pred_masks  = (const float*)d_in[3];  // [100,800,800]
    const float* gt_boxes    = (const float*)d_in[4];  // [20,4]
    float* out = (float*)d_out;

    float* out_flags  = out + (size_t)N_GT * PER4 * 4;  // [20]
    float* out_scores = out_flags + N_GT;               // [20]

    // 2048 blocks = 8 XCDs x 256; grid-stride covers 3.2M float4s (~6/thread)
    fused_kernel<<<2048, 256, 0, stream>>>(
        pred_boxes, pred_scores, mask_score, (const f32x4*)pred_masks,
        gt_boxes, (f32x4*)out, out_flags, out_scores);
}